// Round 9
// baseline (159.565 us; speedup 1.0000x reference)
//
#include <hip/hip_runtime.h>

// VQ-VAE forward via bf16 MFMA distance scan.
//   score(token,code) = dot(x,w) - ||w||^2/2   (maximize == argmin distance)
//   dist_best = -2*score_best;  SSE = sum(xsq) + sum(dist_best)
//
// R12: de-lockstep the codebook stream. All 2048 waves scanned tiles 0..63 in
//     the same order -> chip-wide same-line request convergence (hot L2
//     bank/channel, effective latency ~1000s of cycles). Each wave now starts
//     at rot=(4*block+wv)&63 and wraps, spreading requests uniformly over the
//     codebook. In-loop argmax gains an explicit (score, smaller-index)
//     tie-break so the result is scan-order independent.
//     Kept: R8 ring-4 structure (ring-8 is VGPR-futile per R11), no LDS
//     staging (R10), no fences (R7), no occupancy squeeze (R9).
//
// ws layout: [0,4096) u32 counts[1024] | [4096,4104) double sse
//            [5120,5124) u32 ticket
//            [8192,12288) float wnh[1024] (= -0.5||w||^2)
//            [16384,16384+131072) bf16 W_swz: uint4[K/16][8][64] wave-read order

typedef __bf16          bf16x8  __attribute__((ext_vector_type(8)));
typedef float           f32x4   __attribute__((ext_vector_type(4)));
typedef unsigned short  ushortx8 __attribute__((ext_vector_type(8)));

constexpr int D = 64;
constexpr int K = 1024;
constexpr int TOKB = 256;             // tokens per block (64/wave x 4 waves)

__device__ __forceinline__ unsigned short f2bf(float f) {
  unsigned u = __builtin_bit_cast(unsigned, f);
  u = (u + 0x7fffu + ((u >> 16) & 1u)) >> 16;  // RNE
  return (unsigned short)u;
}

// 8 threads per code: thread (c,p) converts 32B of row c, shuffle-reduces ||w||^2.
__global__ __launch_bounds__(256) void vq_init(const float* __restrict__ W,
                                               unsigned* __restrict__ counts,
                                               float* __restrict__ wnh,
                                               double* __restrict__ sse,
                                               unsigned* __restrict__ ticket,
                                               uint4* __restrict__ wswz) {
  const int gid = blockIdx.x * 256 + threadIdx.x;  // 0..8191
  const int c = gid >> 3, p = gid & 7;
  const float4* row = reinterpret_cast<const float4*>(W + c * D);
  float4 v0 = row[2 * p], v1 = row[2 * p + 1];
  float s = 0.f;
  s = fmaf(v0.x, v0.x, s); s = fmaf(v0.y, v0.y, s);
  s = fmaf(v0.z, v0.z, s); s = fmaf(v0.w, v0.w, s);
  s = fmaf(v1.x, v1.x, s); s = fmaf(v1.y, v1.y, s);
  s = fmaf(v1.z, v1.z, s); s = fmaf(v1.w, v1.w, s);
  ushortx8 pk;
  pk[0] = f2bf(v0.x); pk[1] = f2bf(v0.y); pk[2] = f2bf(v0.z); pk[3] = f2bf(v0.w);
  pk[4] = f2bf(v1.x); pk[5] = f2bf(v1.y); pk[6] = f2bf(v1.z); pk[7] = f2bf(v1.w);
  // swizzle: wave read b0/b1 at [ct*128 + half*64 + lane], lane = q*16 + cnl.
  const int ct = c >> 4, cnl = c & 15, half = p >> 2, q = p & 3;
  wswz[ct * 128 + half * 64 + q * 16 + cnl] = __builtin_bit_cast(uint4, pk);
  // reduce ||w||^2 across the 8 lanes of this code (aligned 8-lane groups)
  s += __shfl_xor(s, 1, 64);
  s += __shfl_xor(s, 2, 64);
  s += __shfl_xor(s, 4, 64);
  if (p == 0) wnh[c] = -0.5f * s;
  if (gid < K) counts[gid] = 0u;
  if (gid == 0) { *sse = 0.0; *ticket = 0u; }
}

// 256 threads = 4 waves; 64 tokens/wave (4 A-tiles of 16) -> 256 tokens/block.
__global__ __launch_bounds__(256, 2) void vq_main(const float* __restrict__ x,
                                                  const float* __restrict__ Wf,
                                                  const uint4* __restrict__ wswz,
                                                  const float* __restrict__ wnh,
                                                  unsigned* __restrict__ counts,
                                                  double* __restrict__ sse,
                                                  unsigned* __restrict__ ticket,
                                                  float* __restrict__ out,
                                                  int n_tokens) {
  __shared__ unsigned s_hist[K];       // 4 KB
  __shared__ float s_wnh[K];           // 4 KB (-0.5||w||^2, LDS broadcast reads)
  __shared__ unsigned s_idx[TOKB];     // 1 KB
  __shared__ float s_red[4];
  __shared__ unsigned s_ured[4];
  __shared__ unsigned s_last;

  const int tid = threadIdx.x;
  const int wv = tid >> 6, lane = tid & 63;
  const int g = lane >> 4, nl = lane & 15;
  const int tokwg = blockIdx.x * TOKB;
  // Per-wave scan rotation: decorrelate the chip-wide codebook stream.
  const int rot = (int)((blockIdx.x * 4 + wv) & 63);

  for (int i = tid; i < K; i += 256) {
    s_hist[i] = 0u;
    s_wnh[i] = wnh[i];
  }
  __syncthreads();   // hist zero + wnh visible

  // A fragments: lane holds A[m=lane&15][k=(lane>>4)*8+j]; 4 token tiles.
  bf16x8 afrag[4][2];
  float xsq = 0.f;
#pragma unroll
  for (int tt = 0; tt < 4; ++tt) {
#pragma unroll
    for (int s = 0; s < 2; ++s) {
      const float* px = x + (size_t)(tokwg + wv * 64 + tt * 16 + nl) * D + s * 32 + g * 8;
      float4 v0 = *reinterpret_cast<const float4*>(px);
      float4 v1 = *reinterpret_cast<const float4*>(px + 4);
      xsq = fmaf(v0.x, v0.x, xsq); xsq = fmaf(v0.y, v0.y, xsq);
      xsq = fmaf(v0.z, v0.z, xsq); xsq = fmaf(v0.w, v0.w, xsq);
      xsq = fmaf(v1.x, v1.x, xsq); xsq = fmaf(v1.y, v1.y, xsq);
      xsq = fmaf(v1.z, v1.z, xsq); xsq = fmaf(v1.w, v1.w, xsq);
      ushortx8 p;
      p[0] = f2bf(v0.x); p[1] = f2bf(v0.y); p[2] = f2bf(v0.z); p[3] = f2bf(v0.w);
      p[4] = f2bf(v1.x); p[5] = f2bf(v1.y); p[6] = f2bf(v1.z); p[7] = f2bf(v1.w);
      afrag[tt][s] = __builtin_bit_cast(bf16x8, p);
    }
  }

  float best[4][4];
  unsigned bidx[4][4];
#pragma unroll
  for (int tt = 0; tt < 4; ++tt)
#pragma unroll
    for (int j = 0; j < 4; ++j) { best[tt][j] = -3.0e38f; bidx[tt][j] = 0xffffffffu; }

  // One 16-code tile (physical tile index ct): 4 MFMA chains + argmax.
  // Tie-break on equal score keeps the smaller code index -> result is
  // independent of the rotated scan order (matches reference argmin).
  auto process = [&](int ct, uint4 cb0, uint4 cb1) {
    const float w0 = s_wnh[ct * 16 + nl];   // LDS broadcast, off the vmcnt path
    const bf16x8 b0 = __builtin_bit_cast(bf16x8, cb0);
    const bf16x8 b1 = __builtin_bit_cast(bf16x8, cb1);
    const unsigned code0 = (unsigned)(ct * 16 + nl);
#pragma unroll
    for (int tt = 0; tt < 4; ++tt) {
      f32x4 acc = (f32x4){w0, w0, w0, w0};  // C init = -||w||^2/2 (per col)
      acc = __builtin_amdgcn_mfma_f32_16x16x32_bf16(afrag[tt][0], b0, acc, 0, 0, 0);
      acc = __builtin_amdgcn_mfma_f32_16x16x32_bf16(afrag[tt][1], b1, acc, 0, 0, 0);
#pragma unroll
      for (int j = 0; j < 4; ++j) {
        const bool take = (acc[j] > best[tt][j]) ||
                          (acc[j] == best[tt][j] && code0 < bidx[tt][j]);
        if (take) { best[tt][j] = acc[j]; bidx[tt][j] = code0; }
      }
    }
  };

  // ---- barrier-free scan over all 1024 codes, 16 per tile, from L2 ----
  // 4-slot prefetch ring (R8 structure), rotated start: wave scans tiles
  // rot, rot+1, ..., rot+63 (mod 64).
  uint4 p0[4], p1[4];
#pragma unroll
  for (int s = 0; s < 4; ++s) {
    const int ph = (rot + s) & 63;
    p0[s] = wswz[ph * 128 + lane];
    p1[s] = wswz[ph * 128 + 64 + lane];
  }
  for (int ct = 0; ct < K / 16; ct += 4) {
#pragma unroll
    for (int s = 0; s < 4; ++s) {
      const uint4 cb0 = p0[s], cb1 = p1[s];
      const int cur = (rot + ct + s) & 63;
      if (ct + s + 4 < K / 16) {
        const int nxt = (rot + ct + s + 4) & 63;
        p0[s] = wswz[nxt * 128 + lane];
        p1[s] = wswz[nxt * 128 + 64 + lane];
      }
      process(cur, cb0, cb1);
    }
  }

  // Cross-lane argmax over the 16 cols; C/D row = 4*g+j, col = nl.
  float ddist = 0.f;
#pragma unroll
  for (int tt = 0; tt < 4; ++tt) {
#pragma unroll
    for (int j = 0; j < 4; ++j) {
      float b = best[tt][j];
      unsigned bi = bidx[tt][j];
#pragma unroll
      for (int off = 1; off < 16; off <<= 1) {
        float ob = __shfl_xor(b, off, 64);
        unsigned oi = __shfl_xor(bi, off, 64);
        if (ob > b || (ob == b && oi < bi)) { b = ob; bi = oi; }
      }
      if (nl == 0) {
        int tl = wv * 64 + tt * 16 + 4 * g + j;
        s_idx[tl] = bi;
        atomicAdd(&s_hist[bi], 1u);
        ddist = fmaf(-2.0f, b, ddist);  // dist = wsq - 2*dot >= 0
      }
    }
  }

  // Block-reduce SSE contribution: sum(x^2) + sum(dist_best).
  float sv = xsq + ddist;
#pragma unroll
  for (int off = 32; off > 0; off >>= 1) sv += __shfl_down(sv, off, 64);
  if (lane == 0) s_red[wv] = sv;
  __syncthreads();  // also publishes s_idx / orders s_hist atomics
  if (tid == 0) atomicAdd(sse, (double)((s_red[0] + s_red[1]) + (s_red[2] + s_red[3])));

  for (int i = tid; i < K; i += 256) {
    unsigned h = s_hist[i];
    if (h) atomicAdd(&counts[i], h);
  }

  // out = W[idx] (fp32 gather; == x + (q - x) to <=1 ulp).
  const int d4 = tid & 15;
#pragma unroll
  for (int tk = 0; tk < TOKB / 16; ++tk) {
    int tl = tk * 16 + (tid >> 4);
    unsigned ci = s_idx[tl];
    float4 q = *reinterpret_cast<const float4*>(Wf + ci * D + d4 * 4);
    *reinterpret_cast<float4*>(out + (size_t)(tokwg + tl) * D + d4 * 4) = q;
  }

  // ---- fused final: last block to finish does the tail reduction ----
  // NO __threadfence (R7 lesson): counts/sse are device-scope atomic RMWs at
  // the coherence point; the compiler's s_waitcnt vmcnt(0) before s_barrier
  // orders them before the ticket RMW. An agent fence would buffer_inv the
  // XCD L2 and stall every in-flight block (the R4/R5 170us regression).
  __syncthreads();
  if (tid == 0) {
    unsigned t = atomicAdd(ticket, 1u);
    s_last = (t == gridDim.x - 1) ? 1u : 0u;
  }
  __syncthreads();
  if (s_last) {
    const float inv_n = 1.0f / (float)n_tokens;
    float s = 0.f;
    unsigned u = 0;
    for (int c = tid; c < K; c += 256) {
      unsigned cnt = atomicAdd(&counts[c], 0u);  // coherent RMW read
      float p = (float)cnt * inv_n;
      s += p * logf(p + 1e-10f);
      u += (cnt >= 1u) ? 1u : 0u;
    }
#pragma unroll
    for (int off = 32; off > 0; off >>= 1) {
      s += __shfl_down(s, off, 64);
      u += __shfl_down(u, off, 64);
    }
    if (lane == 0) { s_red[wv] = s; s_ured[wv] = u; }
    __syncthreads();
    if (tid == 0) {
      double sv2 = atomicAdd(sse, 0.0);  // coherent read of final SSE
      float s2 = (s_red[0] + s_red[1]) + (s_red[2] + s_red[3]);
      unsigned u2 = s_ured[0] + s_ured[1] + s_ured[2] + s_ured[3];
      double mean = sv2 / ((double)n_tokens * (double)D);
      float* out_tail = out + (size_t)n_tokens * D;
      out_tail[0] = 3.0f * (float)mean;  // q_latent + 2*e_latent
      out_tail[1] = expf(-s2);           // perplexity
      out_tail[2] = (float)u2;           // usage
    }
  }
}

extern "C" void kernel_launch(void* const* d_in, const int* in_sizes, int n_in,
                              void* d_out, int out_size, void* d_ws, size_t ws_size,
                              hipStream_t stream) {
  const float* x = (const float*)d_in[0];
  const float* W = (const float*)d_in[1];
  float* out = (float*)d_out;

  unsigned* counts = (unsigned*)d_ws;
  double* sse = (double*)((char*)d_ws + 4096);
  unsigned* ticket = (unsigned*)((char*)d_ws + 5120);
  float* wnh = (float*)((char*)d_ws + 8192);
  uint4* wswz = (uint4*)((char*)d_ws + 16384);

  const int n_tokens = in_sizes[0] / D;  // 131072
  const int blocks = n_tokens / TOKB;    // 512

  vq_init<<<K * 8 / 256, 256, 0, stream>>>(W, counts, wnh, sse, ticket, wswz);
  vq_main<<<blocks, 256, 0, stream>>>(x, W, wswz, wnh, counts, sse, ticket,
                                      out, n_tokens);
}

// Round 11
// 117.297 us; speedup vs baseline: 1.3604x; 1.3604x over previous
//
#include <hip/hip_runtime.h>

// VQ-VAE forward via bf16 MFMA distance scan.
//   acc(token,code) = (||w||^2/2 + BIAS) - dot(x,w)   (minimize; >0 by bound)
//   dist = xsq + 2*(acc_best - BIAS)
//
// R14 = R13 with the packed-key sign bug fixed. R13's acc = wsq/2 - dot went
//     NEGATIVE for ~half the codes (dist/2 = acc + xsq/2, not acc); negative
//     floats reverse order under signed-int min -> argmin corrupted (usage
//     off by 132). Fix: fold BIAS=0.25 into C-init; |dot| <= ||x||*||w|| <
//     0.096 << 0.25 (chi^2(64) tail ~1e-40), so acc in [0.15,0.35] > 0 and
//     bit-monotonic. Truncation granularity ~3e-5 < bf16 score noise already
//     tolerated. Per-row constants don't affect per-token argmin over codes.
//     Kept: TOKB=512 (128 tok/wave), lockstep scan (R12), ring-4 (R11), no
//     LDS staging (R10), no fences (R7), no forced-occupancy spills (R9).
//
// ws layout: [0,4096) u32 counts[1024] | [4096,4104) double sse
//            [5120,5124) u32 ticket
//            [8192,12288) float wph[1024] (= +0.5||w||^2)
//            [16384,16384+131072) bf16 W_swz: uint4[K/16][8][64] wave-read order

typedef __bf16          bf16x8  __attribute__((ext_vector_type(8)));
typedef float           f32x4   __attribute__((ext_vector_type(4)));
typedef unsigned short  ushortx8 __attribute__((ext_vector_type(8)));

constexpr int D = 64;
constexpr int K = 1024;
constexpr int TOKB = 512;             // tokens per block (128/wave x 4 waves)
constexpr float BIAS = 0.25f;         // positivity bias for packed-key argmin

__device__ __forceinline__ unsigned short f2bf(float f) {
  unsigned u = __builtin_bit_cast(unsigned, f);
  u = (u + 0x7fffu + ((u >> 16) & 1u)) >> 16;  // RNE
  return (unsigned short)u;
}

// 8 threads per code: thread (c,p) converts 32B of row c, shuffle-reduces ||w||^2.
__global__ __launch_bounds__(256) void vq_init(const float* __restrict__ W,
                                               unsigned* __restrict__ counts,
                                               float* __restrict__ wph,
                                               double* __restrict__ sse,
                                               unsigned* __restrict__ ticket,
                                               uint4* __restrict__ wswz) {
  const int gid = blockIdx.x * 256 + threadIdx.x;  // 0..8191
  const int c = gid >> 3, p = gid & 7;
  const float4* row = reinterpret_cast<const float4*>(W + c * D);
  float4 v0 = row[2 * p], v1 = row[2 * p + 1];
  float s = 0.f;
  s = fmaf(v0.x, v0.x, s); s = fmaf(v0.y, v0.y, s);
  s = fmaf(v0.z, v0.z, s); s = fmaf(v0.w, v0.w, s);
  s = fmaf(v1.x, v1.x, s); s = fmaf(v1.y, v1.y, s);
  s = fmaf(v1.z, v1.z, s); s = fmaf(v1.w, v1.w, s);
  ushortx8 pk;
  pk[0] = f2bf(v0.x); pk[1] = f2bf(v0.y); pk[2] = f2bf(v0.z); pk[3] = f2bf(v0.w);
  pk[4] = f2bf(v1.x); pk[5] = f2bf(v1.y); pk[6] = f2bf(v1.z); pk[7] = f2bf(v1.w);
  // swizzle: wave read b0/b1 at [ct*128 + half*64 + lane], lane = q*16 + cnl.
  const int ct = c >> 4, cnl = c & 15, half = p >> 2, q = p & 3;
  wswz[ct * 128 + half * 64 + q * 16 + cnl] = __builtin_bit_cast(uint4, pk);
  // reduce ||w||^2 across the 8 lanes of this code (aligned 8-lane groups)
  s += __shfl_xor(s, 1, 64);
  s += __shfl_xor(s, 2, 64);
  s += __shfl_xor(s, 4, 64);
  if (p == 0) wph[c] = 0.5f * s;       // +half-norm (bias added at LDS stage)
  if (gid < K) counts[gid] = 0u;
  if (gid == 0) { *sse = 0.0; *ticket = 0u; }
}

// 256 threads = 4 waves; 128 tokens/wave (8 A-tiles of 16) -> 512 tokens/block.
__global__ __launch_bounds__(256, 1) void vq_main(const float* __restrict__ x,
                                                  const float* __restrict__ Wf,
                                                  const uint4* __restrict__ wswz,
                                                  const float* __restrict__ wph,
                                                  unsigned* __restrict__ counts,
                                                  double* __restrict__ sse,
                                                  unsigned* __restrict__ ticket,
                                                  float* __restrict__ out,
                                                  int n_tokens) {
  __shared__ unsigned s_hist[K];       // 4 KB
  __shared__ float s_wphb[K];          // 4 KB (+0.5||w||^2 + BIAS)
  __shared__ unsigned s_idx[TOKB];     // 2 KB
  __shared__ float s_red[4];
  __shared__ unsigned s_ured[4];
  __shared__ unsigned s_last;

  const int tid = threadIdx.x;
  const int wv = tid >> 6, lane = tid & 63;
  const int g = lane >> 4, nl = lane & 15;
  const int tokwg = blockIdx.x * TOKB;

  for (int i = tid; i < K; i += 256) {
    s_hist[i] = 0u;
    s_wphb[i] = wph[i] + BIAS;
  }
  __syncthreads();   // hist zero + wphb visible

  // A fragments (NEGATED x): lane holds -A[m=lane&15][k=(lane>>4)*8+j];
  // 8 token tiles. acc = (wsq/2 + BIAS) + (-x).w  in [0.15, 0.35] > 0.
  bf16x8 afrag[8][2];
  float xsq = 0.f;
#pragma unroll
  for (int tt = 0; tt < 8; ++tt) {
#pragma unroll
    for (int s = 0; s < 2; ++s) {
      const float* px = x + (size_t)(tokwg + wv * 128 + tt * 16 + nl) * D + s * 32 + g * 8;
      float4 v0 = *reinterpret_cast<const float4*>(px);
      float4 v1 = *reinterpret_cast<const float4*>(px + 4);
      xsq = fmaf(v0.x, v0.x, xsq); xsq = fmaf(v0.y, v0.y, xsq);
      xsq = fmaf(v0.z, v0.z, xsq); xsq = fmaf(v0.w, v0.w, xsq);
      xsq = fmaf(v1.x, v1.x, xsq); xsq = fmaf(v1.y, v1.y, xsq);
      xsq = fmaf(v1.z, v1.z, xsq); xsq = fmaf(v1.w, v1.w, xsq);
      ushortx8 p;
      p[0] = f2bf(v0.x); p[1] = f2bf(v0.y); p[2] = f2bf(v0.z); p[3] = f2bf(v0.w);
      p[4] = f2bf(v1.x); p[5] = f2bf(v1.y); p[6] = f2bf(v1.z); p[7] = f2bf(v1.w);
#pragma unroll
      for (int j = 0; j < 8; ++j) p[j] ^= 0x8000;   // negate (exact sign flip)
      afrag[tt][s] = __builtin_bit_cast(bf16x8, p);
    }
  }

  // Packed argmin keys: upper 22 bits = biased score (POSITIVE float, hence
  // bit-monotonic under signed min), low 10 bits = code. v_min_i32 keeps min
  // score, smaller index on tie (matches argmin-first semantics).
  int key[8][4];
#pragma unroll
  for (int tt = 0; tt < 8; ++tt)
#pragma unroll
    for (int j = 0; j < 4; ++j) key[tt][j] = 0x7fffffff;

  // One 16-code tile: 8 MFMA chains + key-min bookkeeping.
  auto process = [&](int ct, uint4 cb0, uint4 cb1) {
    const float w0 = s_wphb[ct * 16 + nl];  // LDS broadcast, off the vmcnt path
    const bf16x8 b0 = __builtin_bit_cast(bf16x8, cb0);
    const bf16x8 b1 = __builtin_bit_cast(bf16x8, cb1);
    const int code0 = ct * 16 + nl;
#pragma unroll
    for (int tt = 0; tt < 8; ++tt) {
      f32x4 acc = (f32x4){w0, w0, w0, w0};  // C init = wsq/2 + BIAS (per col)
      acc = __builtin_amdgcn_mfma_f32_16x16x32_bf16(afrag[tt][0], b0, acc, 0, 0, 0);
      acc = __builtin_amdgcn_mfma_f32_16x16x32_bf16(afrag[tt][1], b1, acc, 0, 0, 0);
#pragma unroll
      for (int j = 0; j < 4; ++j) {
        const int kb = (int)((__builtin_bit_cast(unsigned, acc[j]) & 0xfffffc00u)
                             | (unsigned)code0);
        if (kb < key[tt][j]) key[tt][j] = kb;   // v_min_i32
      }
    }
  };

  // ---- barrier-free lockstep scan over all 1024 codes, 16/tile, from L1/L2.
  // Same order for every wave: waves on a CU share the same hot window
  // (cross-wave L1 locality - R12 showed rotation thrashes it). Ring-4.
  uint4 p0[4], p1[4];
#pragma unroll
  for (int s = 0; s < 4; ++s) {
    p0[s] = wswz[s * 128 + lane];
    p1[s] = wswz[s * 128 + 64 + lane];
  }
  for (int ct = 0; ct < K / 16; ct += 4) {
#pragma unroll
    for (int s = 0; s < 4; ++s) {
      const uint4 cb0 = p0[s], cb1 = p1[s];
      if (ct + s + 4 < K / 16) {
        p0[s] = wswz[(ct + s + 4) * 128 + lane];
        p1[s] = wswz[(ct + s + 4) * 128 + 64 + lane];
      }
      process(ct + s, cb0, cb1);
    }
  }

  // Cross-lane argmin over the 16 cols; C/D row = 4*g+j, col = nl.
  float ddist = 0.f;
#pragma unroll
  for (int tt = 0; tt < 8; ++tt) {
#pragma unroll
    for (int j = 0; j < 4; ++j) {
      int k = key[tt][j];
#pragma unroll
      for (int off = 1; off < 16; off <<= 1) {
        const int ok = __shfl_xor(k, off, 64);
        if (ok < k) k = ok;
      }
      if (nl == 0) {
        const unsigned bi = (unsigned)k & 0x3ffu;
        const float d2 = __builtin_bit_cast(float, (unsigned)k & 0xfffffc00u) - BIAS;
        int tl = wv * 128 + tt * 16 + 4 * g + j;
        s_idx[tl] = bi;
        atomicAdd(&s_hist[bi], 1u);
        ddist = fmaf(2.0f, d2, ddist);  // dist = xsq + 2*(wsq/2 - dot)
      }
    }
  }

  // Block-reduce SSE contribution: sum(x^2) + sum(dist_best).
  float sv = xsq + ddist;
#pragma unroll
  for (int off = 32; off > 0; off >>= 1) sv += __shfl_down(sv, off, 64);
  if (lane == 0) s_red[wv] = sv;
  __syncthreads();  // also publishes s_idx / orders s_hist atomics
  if (tid == 0) atomicAdd(sse, (double)((s_red[0] + s_red[1]) + (s_red[2] + s_red[3])));

  for (int i = tid; i < K; i += 256) {
    unsigned h = s_hist[i];
    if (h) atomicAdd(&counts[i], h);
  }

  // out = W[idx] (fp32 gather; == x + (q - x) to <=1 ulp).
  const int d4 = tid & 15;
#pragma unroll
  for (int tk = 0; tk < TOKB / 16; ++tk) {
    int tl = tk * 16 + (tid >> 4);
    unsigned ci = s_idx[tl];
    float4 q = *reinterpret_cast<const float4*>(Wf + ci * D + d4 * 4);
    *reinterpret_cast<float4*>(out + (size_t)(tokwg + tl) * D + d4 * 4) = q;
  }

  // ---- fused final: last block to finish does the tail reduction ----
  // NO __threadfence (R7 lesson): counts/sse are device-scope atomic RMWs at
  // the coherence point; the compiler's s_waitcnt vmcnt(0) before s_barrier
  // orders them before the ticket RMW. An agent fence would buffer_inv the
  // XCD L2 and stall every in-flight block (the R4/R5 170us regression).
  __syncthreads();
  if (tid == 0) {
    unsigned t = atomicAdd(ticket, 1u);
    s_last = (t == gridDim.x - 1) ? 1u : 0u;
  }
  __syncthreads();
  if (s_last) {
    const float inv_n = 1.0f / (float)n_tokens;
    float s = 0.f;
    unsigned u = 0;
    for (int c = tid; c < K; c += 256) {
      unsigned cnt = atomicAdd(&counts[c], 0u);  // coherent RMW read
      float p = (float)cnt * inv_n;
      s += p * logf(p + 1e-10f);
      u += (cnt >= 1u) ? 1u : 0u;
    }
#pragma unroll
    for (int off = 32; off > 0; off >>= 1) {
      s += __shfl_down(s, off, 64);
      u += __shfl_down(u, off, 64);
    }
    if (lane == 0) { s_red[wv] = s; s_ured[wv] = u; }
    __syncthreads();
    if (tid == 0) {
      double sv2 = atomicAdd(sse, 0.0);  // coherent read of final SSE
      float s2 = (s_red[0] + s_red[1]) + (s_red[2] + s_red[3]);
      unsigned u2 = s_ured[0] + s_ured[1] + s_ured[2] + s_ured[3];
      double mean = sv2 / ((double)n_tokens * (double)D);
      float* out_tail = out + (size_t)n_tokens * D;
      out_tail[0] = 3.0f * (float)mean;  // q_latent + 2*e_latent
      out_tail[1] = expf(-s2);           // perplexity
      out_tail[2] = (float)u2;           // usage
    }
  }
}

extern "C" void kernel_launch(void* const* d_in, const int* in_sizes, int n_in,
                              void* d_out, int out_size, void* d_ws, size_t ws_size,
                              hipStream_t stream) {
  const float* x = (const float*)d_in[0];
  const float* W = (const float*)d_in[1];
  float* out = (float*)d_out;

  unsigned* counts = (unsigned*)d_ws;
  double* sse = (double*)((char*)d_ws + 4096);
  unsigned* ticket = (unsigned*)((char*)d_ws + 5120);
  float* wph = (float*)((char*)d_ws + 8192);
  uint4* wswz = (uint4*)((char*)d_ws + 16384);

  const int n_tokens = in_sizes[0] / D;  // 131072
  const int blocks = n_tokens / TOKB;    // 256

  vq_init<<<K * 8 / 256, 256, 0, stream>>>(W, counts, wph, sse, ticket, wswz);
  vq_main<<<blocks, 256, 0, stream>>>(x, W, wswz, wph, counts, sse, ticket,
                                      out, n_tokens);
}

// Round 12
// 116.107 us; speedup vs baseline: 1.3743x; 1.0102x over previous
//
#include <hip/hip_runtime.h>

// VQ-VAE forward via bf16 MFMA distance scan.
//   acc(token,code) = (||w||^2/2 + BIAS) - dot(x,w)   (minimize; >0 by bound)
//   dist = xsq + 2*(acc_best - BIAS)
//
// R15: WHOLE codebook in LDS (128KB s_w + 13KB misc = 141KB < 160KB/CU).
//     R14's residual stall = contended-L2: 1024 waves each privately stream
//     128KB (131MB L2 reads, bursty lockstep -> ~1000cyc effective latency).
//     Now: one-shot global_load_lds stage (layout already linear wave-read
//     order), ONE barrier, whole scan from LDS via conflict-free ds_read_b128
//     with 1-deep reg prefetch. Fixes R10's failure modes: no VGPR cap (no
//     spills), no per-chunk barriers, no re-staging per block.
//     Kept: packed-key argmin w/ BIAS=0.25 (R14), TOKB=512, lockstep scan
//     (R12), no fences (R7).
//
// ws layout: [0,4096) u32 counts[1024] | [4096,4104) double sse
//            [5120,5124) u32 ticket
//            [8192,12288) float wph[1024] (= +0.5||w||^2)
//            [16384,16384+131072) bf16 W_swz: uint4[K/16][8][64] wave-read order

typedef __bf16          bf16x8  __attribute__((ext_vector_type(8)));
typedef float           f32x4   __attribute__((ext_vector_type(4)));
typedef unsigned short  ushortx8 __attribute__((ext_vector_type(8)));

constexpr int D = 64;
constexpr int K = 1024;
constexpr int TOKB = 512;             // tokens per block (128/wave x 4 waves)
constexpr float BIAS = 0.25f;         // positivity bias for packed-key argmin

__device__ __forceinline__ unsigned short f2bf(float f) {
  unsigned u = __builtin_bit_cast(unsigned, f);
  u = (u + 0x7fffu + ((u >> 16) & 1u)) >> 16;  // RNE
  return (unsigned short)u;
}

// 8 threads per code: thread (c,p) converts 32B of row c, shuffle-reduces ||w||^2.
__global__ __launch_bounds__(256) void vq_init(const float* __restrict__ W,
                                               unsigned* __restrict__ counts,
                                               float* __restrict__ wph,
                                               double* __restrict__ sse,
                                               unsigned* __restrict__ ticket,
                                               uint4* __restrict__ wswz) {
  const int gid = blockIdx.x * 256 + threadIdx.x;  // 0..8191
  const int c = gid >> 3, p = gid & 7;
  const float4* row = reinterpret_cast<const float4*>(W + c * D);
  float4 v0 = row[2 * p], v1 = row[2 * p + 1];
  float s = 0.f;
  s = fmaf(v0.x, v0.x, s); s = fmaf(v0.y, v0.y, s);
  s = fmaf(v0.z, v0.z, s); s = fmaf(v0.w, v0.w, s);
  s = fmaf(v1.x, v1.x, s); s = fmaf(v1.y, v1.y, s);
  s = fmaf(v1.z, v1.z, s); s = fmaf(v1.w, v1.w, s);
  ushortx8 pk;
  pk[0] = f2bf(v0.x); pk[1] = f2bf(v0.y); pk[2] = f2bf(v0.z); pk[3] = f2bf(v0.w);
  pk[4] = f2bf(v1.x); pk[5] = f2bf(v1.y); pk[6] = f2bf(v1.z); pk[7] = f2bf(v1.w);
  // swizzle: wave read b0/b1 at [ct*128 + half*64 + lane], lane = q*16 + cnl.
  const int ct = c >> 4, cnl = c & 15, half = p >> 2, q = p & 3;
  wswz[ct * 128 + half * 64 + q * 16 + cnl] = __builtin_bit_cast(uint4, pk);
  // reduce ||w||^2 across the 8 lanes of this code (aligned 8-lane groups)
  s += __shfl_xor(s, 1, 64);
  s += __shfl_xor(s, 2, 64);
  s += __shfl_xor(s, 4, 64);
  if (p == 0) wph[c] = 0.5f * s;       // +half-norm (bias added at LDS stage)
  if (gid < K) counts[gid] = 0u;
  if (gid == 0) { *sse = 0.0; *ticket = 0u; }
}

// 256 threads = 4 waves; 128 tokens/wave (8 A-tiles of 16) -> 512 tokens/block.
// 141KB LDS -> 1 block/CU; grid 256 = one block per CU.
__global__ __launch_bounds__(256, 1) void vq_main(const float* __restrict__ x,
                                                  const float* __restrict__ Wf,
                                                  const uint4* __restrict__ wswz,
                                                  const float* __restrict__ wph,
                                                  unsigned* __restrict__ counts,
                                                  double* __restrict__ sse,
                                                  unsigned* __restrict__ ticket,
                                                  float* __restrict__ out,
                                                  int n_tokens) {
  __shared__ uint4 s_w[K * 8];         // 128 KB: whole swizzled codebook
  __shared__ unsigned s_hist[K];       // 4 KB
  __shared__ float s_wphb[K];          // 4 KB (+0.5||w||^2 + BIAS)
  __shared__ unsigned s_idx[TOKB];     // 2 KB
  __shared__ float s_red[4];
  __shared__ unsigned s_ured[4];
  __shared__ unsigned s_last;

  const int tid = threadIdx.x;
  const int wv = tid >> 6, lane = tid & 63;
  const int g = lane >> 4, nl = lane & 15;
  const int tokwg = blockIdx.x * TOKB;

  // ---- one-shot stage: whole codebook -> LDS via global_load_lds.
  // LDS dest = wave-uniform base + lane*16 (linear), as the DMA requires.
  // 32 wave-instructions x 1KB each; all in flight, drained by the barrier.
#pragma unroll
  for (int r = 0; r < 32; ++r) {
    __builtin_amdgcn_global_load_lds(
        (const __attribute__((address_space(1))) uint4*)(wswz + r * 256 + tid),
        (__attribute__((address_space(3))) uint4*)&s_w[r * 256 + tid],
        16, 0, 0);
  }
  for (int i = tid; i < K; i += 256) {
    s_hist[i] = 0u;
    s_wphb[i] = wph[i] + BIAS;
  }

  // A fragments (NEGATED x): lane holds -A[m=lane&15][k=(lane>>4)*8+j];
  // 8 token tiles. acc = (wsq/2 + BIAS) + (-x).w  in [0.15, 0.35] > 0.
  bf16x8 afrag[8][2];
  float xsq = 0.f;
#pragma unroll
  for (int tt = 0; tt < 8; ++tt) {
#pragma unroll
    for (int s = 0; s < 2; ++s) {
      const float* px = x + (size_t)(tokwg + wv * 128 + tt * 16 + nl) * D + s * 32 + g * 8;
      float4 v0 = *reinterpret_cast<const float4*>(px);
      float4 v1 = *reinterpret_cast<const float4*>(px + 4);
      xsq = fmaf(v0.x, v0.x, xsq); xsq = fmaf(v0.y, v0.y, xsq);
      xsq = fmaf(v0.z, v0.z, xsq); xsq = fmaf(v0.w, v0.w, xsq);
      xsq = fmaf(v1.x, v1.x, xsq); xsq = fmaf(v1.y, v1.y, xsq);
      xsq = fmaf(v1.z, v1.z, xsq); xsq = fmaf(v1.w, v1.w, xsq);
      ushortx8 p;
      p[0] = f2bf(v0.x); p[1] = f2bf(v0.y); p[2] = f2bf(v0.z); p[3] = f2bf(v0.w);
      p[4] = f2bf(v1.x); p[5] = f2bf(v1.y); p[6] = f2bf(v1.z); p[7] = f2bf(v1.w);
#pragma unroll
      for (int j = 0; j < 8; ++j) p[j] ^= 0x8000;   // negate (exact sign flip)
      afrag[tt][s] = __builtin_bit_cast(bf16x8, p);
    }
  }

  // Packed argmin keys: upper 22 bits = biased score (positive float, hence
  // bit-monotonic under signed min), low 10 bits = code. v_min_i32 keeps min
  // score, smaller index on tie (matches argmin-first semantics).
  int key[8][4];
#pragma unroll
  for (int tt = 0; tt < 8; ++tt)
#pragma unroll
    for (int j = 0; j < 4; ++j) key[tt][j] = 0x7fffffff;

  // One 16-code tile: 8 MFMA chains + key-min bookkeeping.
  auto process = [&](int ct, uint4 cb0, uint4 cb1) {
    const float w0 = s_wphb[ct * 16 + nl];
    const bf16x8 b0 = __builtin_bit_cast(bf16x8, cb0);
    const bf16x8 b1 = __builtin_bit_cast(bf16x8, cb1);
    const int code0 = ct * 16 + nl;
#pragma unroll
    for (int tt = 0; tt < 8; ++tt) {
      f32x4 acc = (f32x4){w0, w0, w0, w0};  // C init = wsq/2 + BIAS (per col)
      acc = __builtin_amdgcn_mfma_f32_16x16x32_bf16(afrag[tt][0], b0, acc, 0, 0, 0);
      acc = __builtin_amdgcn_mfma_f32_16x16x32_bf16(afrag[tt][1], b1, acc, 0, 0, 0);
#pragma unroll
      for (int j = 0; j < 4; ++j) {
        const int kb = (int)((__builtin_bit_cast(unsigned, acc[j]) & 0xfffffc00u)
                             | (unsigned)code0);
        if (kb < key[tt][j]) key[tt][j] = kb;   // v_min_i32
      }
    }
  };

  __syncthreads();   // stage DMA drained (vmcnt0 before barrier), hist/wphb live

  // ---- scan all 1024 codes from LDS: conflict-free ds_read_b128
  // (consecutive lanes -> consecutive 16B), 1-deep register prefetch hides
  // ~120cyc LDS latency under ~300cyc of tile work. Zero L2 traffic here.
  uint4 c0 = s_w[lane], c1 = s_w[64 + lane];
#pragma unroll 4
  for (int ct = 0; ct < K / 16; ++ct) {
    uint4 n0, n1;
    if (ct + 1 < K / 16) {
      n0 = s_w[(ct + 1) * 128 + lane];
      n1 = s_w[(ct + 1) * 128 + 64 + lane];
    }
    process(ct, c0, c1);
    c0 = n0; c1 = n1;
  }

  // Cross-lane argmin over the 16 cols; C/D row = 4*g+j, col = nl.
  float ddist = 0.f;
#pragma unroll
  for (int tt = 0; tt < 8; ++tt) {
#pragma unroll
    for (int j = 0; j < 4; ++j) {
      int k = key[tt][j];
#pragma unroll
      for (int off = 1; off < 16; off <<= 1) {
        const int ok = __shfl_xor(k, off, 64);
        if (ok < k) k = ok;
      }
      if (nl == 0) {
        const unsigned bi = (unsigned)k & 0x3ffu;
        const float d2 = __builtin_bit_cast(float, (unsigned)k & 0xfffffc00u) - BIAS;
        int tl = wv * 128 + tt * 16 + 4 * g + j;
        s_idx[tl] = bi;
        atomicAdd(&s_hist[bi], 1u);
        ddist = fmaf(2.0f, d2, ddist);  // dist = xsq + 2*(wsq/2 - dot)
      }
    }
  }

  // Block-reduce SSE contribution: sum(x^2) + sum(dist_best).
  float sv = xsq + ddist;
#pragma unroll
  for (int off = 32; off > 0; off >>= 1) sv += __shfl_down(sv, off, 64);
  if (lane == 0) s_red[wv] = sv;
  __syncthreads();  // also publishes s_idx / orders s_hist atomics
  if (tid == 0) atomicAdd(sse, (double)((s_red[0] + s_red[1]) + (s_red[2] + s_red[3])));

  for (int i = tid; i < K; i += 256) {
    unsigned h = s_hist[i];
    if (h) atomicAdd(&counts[i], h);
  }

  // out = W[idx] (fp32 gather; == x + (q - x) to <=1 ulp).
  const int d4 = tid & 15;
#pragma unroll
  for (int tk = 0; tk < TOKB / 16; ++tk) {
    int tl = tk * 16 + (tid >> 4);
    unsigned ci = s_idx[tl];
    float4 q = *reinterpret_cast<const float4*>(Wf + ci * D + d4 * 4);
    *reinterpret_cast<float4*>(out + (size_t)(tokwg + tl) * D + d4 * 4) = q;
  }

  // ---- fused final: last block to finish does the tail reduction ----
  // NO __threadfence (R7 lesson): counts/sse are device-scope atomic RMWs at
  // the coherence point; the compiler's s_waitcnt vmcnt(0) before s_barrier
  // orders them before the ticket RMW. An agent fence would buffer_inv the
  // XCD L2 and stall every in-flight block (the R4/R5 170us regression).
  __syncthreads();
  if (tid == 0) {
    unsigned t = atomicAdd(ticket, 1u);
    s_last = (t == gridDim.x - 1) ? 1u : 0u;
  }
  __syncthreads();
  if (s_last) {
    const float inv_n = 1.0f / (float)n_tokens;
    float s = 0.f;
    unsigned u = 0;
    for (int c = tid; c < K; c += 256) {
      unsigned cnt = atomicAdd(&counts[c], 0u);  // coherent RMW read
      float p = (float)cnt * inv_n;
      s += p * logf(p + 1e-10f);
      u += (cnt >= 1u) ? 1u : 0u;
    }
#pragma unroll
    for (int off = 32; off > 0; off >>= 1) {
      s += __shfl_down(s, off, 64);
      u += __shfl_down(u, off, 64);
    }
    if (lane == 0) { s_red[wv] = s; s_ured[wv] = u; }
    __syncthreads();
    if (tid == 0) {
      double sv2 = atomicAdd(sse, 0.0);  // coherent read of final SSE
      float s2 = (s_red[0] + s_red[1]) + (s_red[2] + s_red[3]);
      unsigned u2 = s_ured[0] + s_ured[1] + s_ured[2] + s_ured[3];
      double mean = sv2 / ((double)n_tokens * (double)D);
      float* out_tail = out + (size_t)n_tokens * D;
      out_tail[0] = 3.0f * (float)mean;  // q_latent + 2*e_latent
      out_tail[1] = expf(-s2);           // perplexity
      out_tail[2] = (float)u2;           // usage
    }
  }
}

extern "C" void kernel_launch(void* const* d_in, const int* in_sizes, int n_in,
                              void* d_out, int out_size, void* d_ws, size_t ws_size,
                              hipStream_t stream) {
  const float* x = (const float*)d_in[0];
  const float* W = (const float*)d_in[1];
  float* out = (float*)d_out;

  unsigned* counts = (unsigned*)d_ws;
  double* sse = (double*)((char*)d_ws + 4096);
  unsigned* ticket = (unsigned*)((char*)d_ws + 5120);
  float* wph = (float*)((char*)d_ws + 8192);
  uint4* wswz = (uint4*)((char*)d_ws + 16384);

  const int n_tokens = in_sizes[0] / D;  // 131072
  const int blocks = n_tokens / TOKB;    // 256

  vq_init<<<K * 8 / 256, 256, 0, stream>>>(W, counts, wph, sse, ticket, wswz);
  vq_main<<<blocks, 256, 0, stream>>>(x, W, wswz, wph, counts, sse, ticket,
                                      out, n_tokens);
}

// Round 13
// 107.794 us; speedup vs baseline: 1.4803x; 1.0771x over previous
//
#include <hip/hip_runtime.h>

// VQ-VAE forward via bf16 MFMA distance scan.
//   acc(token,code) = (||w||^2/2 + BIAS) - dot(x,w)   (minimize; >0 by bound)
//   dist = xsq + 2*(acc_best - BIAS)
//
// R16: 512-thread blocks (8 waves) on the R15 LDS-resident-codebook structure.
//     R15 falsified L2-contention: zero in-scan L2 traffic moved nothing ->
//     the 67% stall fraction is exposed dep-latency at 1 wave/SIMD. Same
//     grid (256 = 1 block/CU, forced by 142KB LDS), same TOKB=512, but 8
//     waves/block = 2 waves/SIMD; each wave owns 64 tokens (R8's proven
//     shape: afrag[4], key[4][4]) -> stalls in one wave covered by the other.
//     Kept: packed-key argmin BIAS=0.25 (R14), one-shot global_load_lds stage
//     + single barrier (R15), lockstep scan (R12), no fences (R7), no
//     forced-occupancy spills (R9).
//
// ws layout: [0,4096) u32 counts[1024] | [4096,4104) double sse
//            [5120,5124) u32 ticket
//            [8192,12288) float wph[1024] (= +0.5||w||^2)
//            [16384,16384+131072) bf16 W_swz: uint4[K/16][8][64] wave-read order

typedef __bf16          bf16x8  __attribute__((ext_vector_type(8)));
typedef float           f32x4   __attribute__((ext_vector_type(4)));
typedef unsigned short  ushortx8 __attribute__((ext_vector_type(8)));

constexpr int D = 64;
constexpr int K = 1024;
constexpr int BLK = 512;              // threads: 8 waves
constexpr int TOKB = 512;             // tokens per block (64/wave x 8 waves)
constexpr float BIAS = 0.25f;         // positivity bias for packed-key argmin

__device__ __forceinline__ unsigned short f2bf(float f) {
  unsigned u = __builtin_bit_cast(unsigned, f);
  u = (u + 0x7fffu + ((u >> 16) & 1u)) >> 16;  // RNE
  return (unsigned short)u;
}

// 8 threads per code: thread (c,p) converts 32B of row c, shuffle-reduces ||w||^2.
__global__ __launch_bounds__(256) void vq_init(const float* __restrict__ W,
                                               unsigned* __restrict__ counts,
                                               float* __restrict__ wph,
                                               double* __restrict__ sse,
                                               unsigned* __restrict__ ticket,
                                               uint4* __restrict__ wswz) {
  const int gid = blockIdx.x * 256 + threadIdx.x;  // 0..8191
  const int c = gid >> 3, p = gid & 7;
  const float4* row = reinterpret_cast<const float4*>(W + c * D);
  float4 v0 = row[2 * p], v1 = row[2 * p + 1];
  float s = 0.f;
  s = fmaf(v0.x, v0.x, s); s = fmaf(v0.y, v0.y, s);
  s = fmaf(v0.z, v0.z, s); s = fmaf(v0.w, v0.w, s);
  s = fmaf(v1.x, v1.x, s); s = fmaf(v1.y, v1.y, s);
  s = fmaf(v1.z, v1.z, s); s = fmaf(v1.w, v1.w, s);
  ushortx8 pk;
  pk[0] = f2bf(v0.x); pk[1] = f2bf(v0.y); pk[2] = f2bf(v0.z); pk[3] = f2bf(v0.w);
  pk[4] = f2bf(v1.x); pk[5] = f2bf(v1.y); pk[6] = f2bf(v1.z); pk[7] = f2bf(v1.w);
  // swizzle: wave read b0/b1 at [ct*128 + half*64 + lane], lane = q*16 + cnl.
  const int ct = c >> 4, cnl = c & 15, half = p >> 2, q = p & 3;
  wswz[ct * 128 + half * 64 + q * 16 + cnl] = __builtin_bit_cast(uint4, pk);
  // reduce ||w||^2 across the 8 lanes of this code (aligned 8-lane groups)
  s += __shfl_xor(s, 1, 64);
  s += __shfl_xor(s, 2, 64);
  s += __shfl_xor(s, 4, 64);
  if (p == 0) wph[c] = 0.5f * s;       // +half-norm (bias added at LDS stage)
  if (gid < K) counts[gid] = 0u;
  if (gid == 0) { *sse = 0.0; *ticket = 0u; }
}

// 512 threads = 8 waves; 64 tokens/wave (4 A-tiles of 16) -> 512 tokens/block.
// 142KB LDS -> 1 block/CU (grid 256), 8 waves = 2 per SIMD.
__global__ __launch_bounds__(512, 1) void vq_main(const float* __restrict__ x,
                                                  const float* __restrict__ Wf,
                                                  const uint4* __restrict__ wswz,
                                                  const float* __restrict__ wph,
                                                  unsigned* __restrict__ counts,
                                                  double* __restrict__ sse,
                                                  unsigned* __restrict__ ticket,
                                                  float* __restrict__ out,
                                                  int n_tokens) {
  __shared__ uint4 s_w[K * 8];         // 128 KB: whole swizzled codebook
  __shared__ unsigned s_hist[K];       // 4 KB
  __shared__ float s_wphb[K];          // 4 KB (+0.5||w||^2 + BIAS)
  __shared__ unsigned s_idx[TOKB];     // 2 KB
  __shared__ float s_red[8];
  __shared__ unsigned s_ured[8];
  __shared__ unsigned s_last;

  const int tid = threadIdx.x;
  const int wv = tid >> 6, lane = tid & 63;
  const int g = lane >> 4, nl = lane & 15;
  const int tokwg = blockIdx.x * TOKB;

  // ---- one-shot stage: whole codebook -> LDS via global_load_lds.
  // LDS dest = wave-uniform base + lane*16 (linear), as the DMA requires.
  // 16 rounds x 512 threads x 16B = 128KB; all in flight, drained by barrier.
#pragma unroll
  for (int r = 0; r < 16; ++r) {
    __builtin_amdgcn_global_load_lds(
        (const __attribute__((address_space(1))) uint4*)(wswz + r * BLK + tid),
        (__attribute__((address_space(3))) uint4*)&s_w[r * BLK + tid],
        16, 0, 0);
  }
  for (int i = tid; i < K; i += BLK) {
    s_hist[i] = 0u;
    s_wphb[i] = wph[i] + BIAS;
  }

  // A fragments (NEGATED x): lane holds -A[m=lane&15][k=(lane>>4)*8+j];
  // 4 token tiles. acc = (wsq/2 + BIAS) + (-x).w  in [0.15, 0.35] > 0.
  bf16x8 afrag[4][2];
  float xsq = 0.f;
#pragma unroll
  for (int tt = 0; tt < 4; ++tt) {
#pragma unroll
    for (int s = 0; s < 2; ++s) {
      const float* px = x + (size_t)(tokwg + wv * 64 + tt * 16 + nl) * D + s * 32 + g * 8;
      float4 v0 = *reinterpret_cast<const float4*>(px);
      float4 v1 = *reinterpret_cast<const float4*>(px + 4);
      xsq = fmaf(v0.x, v0.x, xsq); xsq = fmaf(v0.y, v0.y, xsq);
      xsq = fmaf(v0.z, v0.z, xsq); xsq = fmaf(v0.w, v0.w, xsq);
      xsq = fmaf(v1.x, v1.x, xsq); xsq = fmaf(v1.y, v1.y, xsq);
      xsq = fmaf(v1.z, v1.z, xsq); xsq = fmaf(v1.w, v1.w, xsq);
      ushortx8 p;
      p[0] = f2bf(v0.x); p[1] = f2bf(v0.y); p[2] = f2bf(v0.z); p[3] = f2bf(v0.w);
      p[4] = f2bf(v1.x); p[5] = f2bf(v1.y); p[6] = f2bf(v1.z); p[7] = f2bf(v1.w);
#pragma unroll
      for (int j = 0; j < 8; ++j) p[j] ^= 0x8000;   // negate (exact sign flip)
      afrag[tt][s] = __builtin_bit_cast(bf16x8, p);
    }
  }

  // Packed argmin keys: upper 22 bits = biased score (positive float, hence
  // bit-monotonic under signed min), low 10 bits = code. v_min_i32 keeps min
  // score, smaller index on tie (matches argmin-first semantics).
  int key[4][4];
#pragma unroll
  for (int tt = 0; tt < 4; ++tt)
#pragma unroll
    for (int j = 0; j < 4; ++j) key[tt][j] = 0x7fffffff;

  // One 16-code tile: 4 MFMA chains + key-min bookkeeping.
  auto process = [&](int ct, uint4 cb0, uint4 cb1) {
    const float w0 = s_wphb[ct * 16 + nl];
    const bf16x8 b0 = __builtin_bit_cast(bf16x8, cb0);
    const bf16x8 b1 = __builtin_bit_cast(bf16x8, cb1);
    const int code0 = ct * 16 + nl;
#pragma unroll
    for (int tt = 0; tt < 4; ++tt) {
      f32x4 acc = (f32x4){w0, w0, w0, w0};  // C init = wsq/2 + BIAS (per col)
      acc = __builtin_amdgcn_mfma_f32_16x16x32_bf16(afrag[tt][0], b0, acc, 0, 0, 0);
      acc = __builtin_amdgcn_mfma_f32_16x16x32_bf16(afrag[tt][1], b1, acc, 0, 0, 0);
#pragma unroll
      for (int j = 0; j < 4; ++j) {
        const int kb = (int)((__builtin_bit_cast(unsigned, acc[j]) & 0xfffffc00u)
                             | (unsigned)code0);
        if (kb < key[tt][j]) key[tt][j] = kb;   // v_min_i32
      }
    }
  };

  __syncthreads();   // stage DMA drained (vmcnt0 before barrier), hist/wphb live

  // ---- scan all 1024 codes from LDS: conflict-free ds_read_b128
  // (consecutive lanes -> consecutive 16B), 1-deep register prefetch; the
  // co-resident wave on each SIMD covers remaining dep-latency stalls.
  uint4 c0 = s_w[lane], c1 = s_w[64 + lane];
#pragma unroll 4
  for (int ct = 0; ct < K / 16; ++ct) {
    uint4 n0, n1;
    if (ct + 1 < K / 16) {
      n0 = s_w[(ct + 1) * 128 + lane];
      n1 = s_w[(ct + 1) * 128 + 64 + lane];
    }
    process(ct, c0, c1);
    c0 = n0; c1 = n1;
  }

  // Cross-lane argmin over the 16 cols; C/D row = 4*g+j, col = nl.
  float ddist = 0.f;
#pragma unroll
  for (int tt = 0; tt < 4; ++tt) {
#pragma unroll
    for (int j = 0; j < 4; ++j) {
      int k = key[tt][j];
#pragma unroll
      for (int off = 1; off < 16; off <<= 1) {
        const int ok = __shfl_xor(k, off, 64);
        if (ok < k) k = ok;
      }
      if (nl == 0) {
        const unsigned bi = (unsigned)k & 0x3ffu;
        const float d2 = __builtin_bit_cast(float, (unsigned)k & 0xfffffc00u) - BIAS;
        int tl = wv * 64 + tt * 16 + 4 * g + j;
        s_idx[tl] = bi;
        atomicAdd(&s_hist[bi], 1u);
        ddist = fmaf(2.0f, d2, ddist);  // dist = xsq + 2*(wsq/2 - dot)
      }
    }
  }

  // Block-reduce SSE contribution: sum(x^2) + sum(dist_best).
  float sv = xsq + ddist;
#pragma unroll
  for (int off = 32; off > 0; off >>= 1) sv += __shfl_down(sv, off, 64);
  if (lane == 0) s_red[wv] = sv;
  __syncthreads();  // also publishes s_idx / orders s_hist atomics
  if (tid == 0) {
    float t = 0.f;
#pragma unroll
    for (int w = 0; w < 8; ++w) t += s_red[w];
    atomicAdd(sse, (double)t);
  }

  for (int i = tid; i < K; i += BLK) {
    unsigned h = s_hist[i];
    if (h) atomicAdd(&counts[i], h);
  }

  // out = W[idx] (fp32 gather; == x + (q - x) to <=1 ulp).
  const int d4 = tid & 15;
#pragma unroll
  for (int tk = 0; tk < TOKB / 32; ++tk) {
    int tl = tk * 32 + (tid >> 4);
    unsigned ci = s_idx[tl];
    float4 q = *reinterpret_cast<const float4*>(Wf + ci * D + d4 * 4);
    *reinterpret_cast<float4*>(out + (size_t)(tokwg + tl) * D + d4 * 4) = q;
  }

  // ---- fused final: last block to finish does the tail reduction ----
  // NO __threadfence (R7 lesson): counts/sse are device-scope atomic RMWs at
  // the coherence point; the compiler's s_waitcnt vmcnt(0) before s_barrier
  // orders them before the ticket RMW. An agent fence would buffer_inv the
  // XCD L2 and stall every in-flight block (the R4/R5 170us regression).
  __syncthreads();
  if (tid == 0) {
    unsigned t = atomicAdd(ticket, 1u);
    s_last = (t == gridDim.x - 1) ? 1u : 0u;
  }
  __syncthreads();
  if (s_last) {
    const float inv_n = 1.0f / (float)n_tokens;
    float s = 0.f;
    unsigned u = 0;
    for (int c = tid; c < K; c += BLK) {
      unsigned cnt = atomicAdd(&counts[c], 0u);  // coherent RMW read
      float p = (float)cnt * inv_n;
      s += p * logf(p + 1e-10f);
      u += (cnt >= 1u) ? 1u : 0u;
    }
#pragma unroll
    for (int off = 32; off > 0; off >>= 1) {
      s += __shfl_down(s, off, 64);
      u += __shfl_down(u, off, 64);
    }
    if (lane == 0) { s_red[wv] = s; s_ured[wv] = u; }
    __syncthreads();
    if (tid == 0) {
      double sv2 = atomicAdd(sse, 0.0);  // coherent read of final SSE
      float s2 = 0.f;
      unsigned u2 = 0;
#pragma unroll
      for (int w = 0; w < 8; ++w) { s2 += s_red[w]; u2 += s_ured[w]; }
      double mean = sv2 / ((double)n_tokens * (double)D);
      float* out_tail = out + (size_t)n_tokens * D;
      out_tail[0] = 3.0f * (float)mean;  // q_latent + 2*e_latent
      out_tail[1] = expf(-s2);           // perplexity
      out_tail[2] = (float)u2;           // usage
    }
  }
}

extern "C" void kernel_launch(void* const* d_in, const int* in_sizes, int n_in,
                              void* d_out, int out_size, void* d_ws, size_t ws_size,
                              hipStream_t stream) {
  const float* x = (const float*)d_in[0];
  const float* W = (const float*)d_in[1];
  float* out = (float*)d_out;

  unsigned* counts = (unsigned*)d_ws;
  double* sse = (double*)((char*)d_ws + 4096);
  unsigned* ticket = (unsigned*)((char*)d_ws + 5120);
  float* wph = (float*)((char*)d_ws + 8192);
  uint4* wswz = (uint4*)((char*)d_ws + 16384);

  const int n_tokens = in_sizes[0] / D;  // 131072
  const int blocks = n_tokens / TOKB;    // 256

  vq_init<<<K * 8 / 256, 256, 0, stream>>>(W, counts, wph, sse, ticket, wswz);
  vq_main<<<blocks, BLK, 0, stream>>>(x, W, wswz, wph, counts, sse, ticket,
                                      out, n_tokens);
}